// Round 9
// baseline (581.005 us; speedup 1.0000x reference)
//
#include <hip/hip_runtime.h>
#include <hip/hip_bf16.h>
#include <cstdint>
#include <cstddef>

#define NN     8192
#define INF_   256
#define OUTF   128
#define ALPHA  0.2f
#define LOG2E  1.4426950408889634f
#define JSPLIT 8
#define CHUNK  (NN / JSPLIT)   // 1024 j per block
#define NWIN   (CHUNK / 64)    // 16 windows of 64 j

typedef __bf16 bf16;
typedef unsigned int u32;
typedef unsigned long long u64;
typedef __attribute__((ext_vector_type(8))) __bf16 bf16x8;
typedef __attribute__((ext_vector_type(4))) float f32x4;
typedef __attribute__((ext_vector_type(4))) unsigned int u32x4;
typedef __attribute__((ext_vector_type(8))) unsigned short u16x8;
typedef __attribute__((ext_vector_type(4))) unsigned short u16x4;

// ---------------------------------------------------------------------------
// Dtype detector: read x's first 2048 uint16s as bf16. fp32 storage -> words
// are fp32 mantissa fragments -> huge exponents; bf16 storage -> N(0,1).
// flag = 1 -> tensors are fp32 (confirmed R2-R8); 0 -> bf16.
// ---------------------------------------------------------------------------
__global__ void gat_detect(const unsigned short* __restrict__ xr, int* __restrict__ flag)
{
    const int lane = threadIdx.x & 63;
    float m = 0.f;
    #pragma unroll
    for (int t = 0; t < 32; ++t) {
        const unsigned short u = xr[lane * 32 + t];
        const float v = fabsf((float)__builtin_bit_cast(bf16, u));
        if (v == v) m = fmaxf(m, v);
    }
    #pragma unroll
    for (int d = 1; d < 64; d <<= 1) m = fmaxf(m, __shfl_xor(m, d));
    if (lane == 0) *flag = (m > 100.f) ? 1 : 0;
}

// dtype-generic helpers ------------------------------------------------------
static __device__ __forceinline__ bf16  loadS(const bf16* p)  { return *p; }
static __device__ __forceinline__ bf16  loadS(const float* p) { return (bf16)*p; }
static __device__ __forceinline__ float loadF(const bf16* p)  { return (float)*p; }
static __device__ __forceinline__ float loadF(const float* p) { return *p; }
static __device__ __forceinline__ void load4(const float* p, bf16* d) {
    const f32x4 v = *(const f32x4*)p;
    #pragma unroll
    for (int t = 0; t < 4; ++t) d[t] = (bf16)v[t];
}
static __device__ __forceinline__ void load4(const bf16* p, bf16* d) {
    *(u16x4*)d = *(const u16x4*)p;
}

// ---------------------------------------------------------------------------
// trans transpose: TT[n][k] = bf16(trans[k][n]).
// ---------------------------------------------------------------------------
template <typename T, int WANT>
__global__ void gat_tt(const T* __restrict__ trans, const int* __restrict__ flag,
                       bf16* __restrict__ TT)
{
    if (*flag != WANT) return;
    const int n = blockIdx.x;      // 0..127
    const int k = threadIdx.x;     // 0..255
    TT[n * INF_ + k] = loadS(trans + k * OUTF + n);
}

// ---------------------------------------------------------------------------
// Projection: h = x @ trans, 16 rows/block (grid 512 -> 2 blocks/CU).
// x staged in LDS (17 KB total); TT b-frags read straight from L1/L2 (64 KB
// hot). Outputs tiled HTt[i>>5][n][i&31], e1c/e2c (pre-scaled by log2e).
// ---------------------------------------------------------------------------
template <typename T, int WANT>
__global__ __launch_bounds__(256, 2)
void gat_proj_t(const T* __restrict__ x, const bf16* __restrict__ TT,
                const T* __restrict__ aw, const int* __restrict__ flag,
                bf16* __restrict__ HTt, float* __restrict__ e1c, float* __restrict__ e2c)
{
    if (*flag != WANT) return;

    __shared__ bf16  xs[16][264];
    __shared__ float hl[16][129];

    const int tid  = threadIdx.x;
    const int wave = tid >> 6;
    const int lane = tid & 63;
    const int m    = lane & 15;
    const int q    = lane >> 4;
    const int i0   = blockIdx.x * 16;
    const int n0   = wave * 32;

    // stage x: 16 rows x 256 cols (4096 elems), coalesced, cvt to bf16
    #pragma unroll
    for (int it = 0; it < 4; ++it) {
        const int e = it * 1024 + tid * 4;
        bf16 tmp[4];
        load4(x + (size_t)i0 * INF_ + e, tmp);
        *(u16x4*)&xs[e >> 8][e & 255] = *(u16x4*)tmp;
    }
    __syncthreads();

    f32x4 acc0 = {}, acc1 = {};
    #pragma unroll
    for (int ks = 0; ks < INF_; ks += 32) {
        const bf16x8 a  = *(const bf16x8*)&xs[m][ks + q * 8];          // A[m][k]
        const bf16x8 b0 = *(const bf16x8*)(TT + (n0 + m) * INF_ + ks + q * 8);
        const bf16x8 b1 = *(const bf16x8*)(TT + (n0 + 16 + m) * INF_ + ks + q * 8);
        acc0 = __builtin_amdgcn_mfma_f32_16x16x32_bf16(a, b0, acc0, 0, 0, 0);
        acc1 = __builtin_amdgcn_mfma_f32_16x16x32_bf16(a, b1, acc1, 0, 0, 0);
    }

    // C/D layout: col = lane&15, row = q*4 + reg
    #pragma unroll
    for (int r = 0; r < 4; ++r) {
        hl[q * 4 + r][n0 + m]      = acc0[r];
        hl[q * 4 + r][n0 + 16 + m] = acc1[r];
    }
    __syncthreads();

    {   // e1/e2: 16 threads per row, 8 cols each, reduce over 16 lanes
        const int r = tid >> 4, tn = tid & 15;
        float s1 = 0.f, s2 = 0.f;
        #pragma unroll
        for (int u = 0; u < 8; ++u) {
            const float hv = hl[r][tn * 8 + u];
            s1 += hv * loadF(aw + tn * 8 + u);
            s2 += hv * loadF(aw + OUTF + tn * 8 + u);
        }
        #pragma unroll
        for (int d = 1; d < 16; d <<= 1) {
            s1 += __shfl_xor(s1, d);
            s2 += __shfl_xor(s2, d);
        }
        if (tn == 0) {
            e1c[i0 + r] = s1 * LOG2E;
            e2c[i0 + r] = s2 * LOG2E;
        }
    }

    {   // HTt tiled write: HTt[i>>5][n][i&31]; this block covers half a 32-tile
        const int n = tid >> 1, ih = tid & 1;
        u16x8 pk;
        #pragma unroll
        for (int v = 0; v < 8; ++v)
            pk[v] = __builtin_bit_cast(unsigned short, (bf16)hl[ih * 8 + v][n]);
        bf16* base = HTt + (size_t)(i0 >> 5) * 4096 + n * 32
                   + ((i0 >> 4) & 1) * 16 + ih * 8;
        *(u16x8*)base = pk;
    }
}

// ---------------------------------------------------------------------------
// FUSED adj-stream + masked-softmax-attention partials, 2-window software
// pipeline. Grid 1024 = 4 blocks/CU, no LDS, no barriers. Per 64-j window:
//   16 volatile coalesced dword loads (prefetched ONE WINDOW AHEAD; volatile
//   pins issue order so the scheduler can't sink them to their ballot uses)
//   16 __ballot -> row-masks -> __shfl to A-fragment lanes
//   2 x 32-j MFMA steps vs L2-hot tiled HTt (8 MFMAs each, all 128 features)
// jc = bid & 7 pins each XCD to one HTt/e2c j-slice (L2-resident).
// ---------------------------------------------------------------------------
__global__ __launch_bounds__(256, 4)
void gat_attn(const int* __restrict__ adj, const bf16* __restrict__ HTt,
              const float* __restrict__ e1c, const float* __restrict__ e2c,
              float* __restrict__ numP, float* __restrict__ denP)
{
    const int tid  = threadIdx.x;
    const int wave = tid >> 6;
    const int lane = tid & 63;
    const int m    = lane & 15;
    const int q    = lane >> 4;
    const int jc   = blockIdx.x & (JSPLIT - 1);
    const int ig   = blockIdx.x / JSPLIT;
    const int rbase = ig * 64 + wave * 16;
    const int j0    = jc * CHUNK;

    const float e1 = e1c[rbase + m];
    const volatile int* ap = adj + (size_t)rbase * NN + j0 + lane;
    const float* pe = e2c + j0 + q * 8;
    const bf16*  pb = HTt + (size_t)(j0 >> 5) * 4096 + m * 32 + q * 8;

    f32x4 acc[8] = {};
    float rs = 0.f;

    // one 64-j window: ballot-pack 16 rows, build P, 2 MFMA steps x 8 features
    auto process = [&](const int (&v)[16], int w) {
        u32 mlo = 0, mhi = 0;
        #pragma unroll
        for (int r = 0; r < 16; ++r) {
            const u64 b = __ballot(v[r] != 0);
            if (lane == r) { mlo = (u32)b; mhi = (u32)(b >> 32); }
        }
        const u32 wlo = __shfl(mlo, m);
        const u32 whi = __shfl(mhi, m);

        #pragma unroll
        for (int h = 0; h < 2; ++h) {
            const u32 wb = h ? whi : wlo;
            const int j  = w * 64 + h * 32;
            const f32x4 e2a = *(const f32x4*)(pe + j);
            const f32x4 e2b = *(const f32x4*)(pe + j + 4);

            bf16x8 af;   // A-fragment: A[m][k=q*8+t], leaky-relu in log2 domain
            #pragma unroll
            for (int t = 0; t < 4; ++t) {
                float sv = e1 + e2a[t];
                sv = fmaxf(sv, ALPHA * sv);
                const float p = ((wb >> (q * 8 + t)) & 1u) ? __builtin_amdgcn_exp2f(sv) : 0.f;
                rs += p;
                af[t] = (bf16)p;
            }
            #pragma unroll
            for (int t = 0; t < 4; ++t) {
                float sv = e1 + e2b[t];
                sv = fmaxf(sv, ALPHA * sv);
                const float p = ((wb >> (q * 8 + 4 + t)) & 1u) ? __builtin_amdgcn_exp2f(sv) : 0.f;
                rs += p;
                af[4 + t] = (bf16)p;
            }

            const bf16* pbs = pb + (size_t)(j >> 5) * 4096;
            #pragma unroll
            for (int t = 0; t < 8; ++t) {
                const bf16x8 b = __builtin_bit_cast(bf16x8, *(const u32x4*)(pbs + t * 512));
                acc[t] = __builtin_amdgcn_mfma_f32_16x16x32_bf16(af, b, acc[t], 0, 0, 0);
            }
        }
    };

    int va[16], vb[16];
    #pragma unroll
    for (int r = 0; r < 16; ++r) va[r] = ap[(size_t)r * NN];          // window 0

    for (int w = 0; w < NWIN; w += 2) {
        #pragma unroll
        for (int r = 0; r < 16; ++r)                                   // window w+1
            vb[r] = ap[(size_t)r * NN + (w + 1) * 64];
        process(va, w);
        const int wn = (w + 2 < NWIN) ? w + 2 : NWIN - 1;              // clamp: L1-hot reload
        #pragma unroll
        for (int r = 0; r < 16; ++r)                                   // window w+2
            va[r] = ap[(size_t)r * NN + wn * 64];
        process(vb, w + 1);
    }

    // row-sum: lanes {m, m+16, m+32, m+48} hold the 4 q-slices of row m
    rs += __shfl_xor(rs, 16);
    rs += __shfl_xor(rs, 32);
    if (lane < 16) denP[(size_t)jc * NN + rbase + m] = rs;

    // C/D layout: col = lane&15, row = q*4 + r -> unique partial slot
    #pragma unroll
    for (int t = 0; t < 8; ++t)
        #pragma unroll
        for (int r = 0; r < 4; ++r)
            numP[((size_t)jc * NN + rbase + q * 4 + r) * OUTF + t * 16 + m] = acc[t][r];
}

// ---------------------------------------------------------------------------
// Finalize: out = elu( (sum_s numP) / (sum_s denP) )
// ---------------------------------------------------------------------------
__global__ __launch_bounds__(256)
void gat_fin(const float* __restrict__ numP, const float* __restrict__ denP,
             const int* __restrict__ flag, void* __restrict__ outv)
{
    const int g  = blockIdx.x * 256 + threadIdx.x;   // one thread per 4 elems
    const int i  = g >> 5;
    const int c4 = g & 31;
    float d = 0.f;
    f32x4 v = {0.f, 0.f, 0.f, 0.f};
    #pragma unroll
    for (int s = 0; s < JSPLIT; ++s) {
        d += denP[(size_t)s * NN + i];
        const f32x4 u = *(const f32x4*)(numP + ((size_t)s * NN + i) * OUTF + c4 * 4);
        #pragma unroll
        for (int t = 0; t < 4; ++t) v[t] += u[t];
    }
    #pragma unroll
    for (int t = 0; t < 4; ++t) {
        const float u = v[t] / d;
        v[t] = (u > 0.f) ? u : __builtin_amdgcn_exp2f(u * LOG2E) - 1.f;  // elu
    }
    const size_t off = (size_t)i * OUTF + c4 * 4;
    if (*flag) {
        *(f32x4*)((float*)outv + off) = v;
    } else {
        u16x4 pk;
        #pragma unroll
        for (int t = 0; t < 4; ++t)
            pk[t] = __builtin_bit_cast(unsigned short, (bf16)v[t]);
        *(u16x4*)((__hip_bfloat16*)outv + off) = pk;
    }
}

// ---------------------------------------------------------------------------
extern "C" void kernel_launch(void* const* d_in, const int* in_sizes, int n_in,
                              void* d_out, int out_size, void* d_ws, size_t ws_size,
                              hipStream_t stream)
{
    const int* adj = (const int*)d_in[1];

    // ws layout (bytes):
    // HTt 2MB | e1c 32KB | e2c 32KB | flag 256B | TT 64KB | numP 32MB | denP 256KB
    char* w = (char*)d_ws;
    bf16*  HTt   = (bf16*)w;   w += (size_t)OUTF * NN * 2;
    float* e1c   = (float*)w;  w += NN * 4;
    float* e2c   = (float*)w;  w += NN * 4;
    int*   flag  = (int*)w;    w += 256;
    bf16*  TT    = (bf16*)w;   w += (size_t)OUTF * INF_ * 2;
    float* numP  = (float*)w;  w += (size_t)JSPLIT * NN * OUTF * 4;
    float* denP  = (float*)w;

    gat_detect<<<1, 64, 0, stream>>>((const unsigned short*)d_in[0], flag);

    gat_tt<float, 1><<<OUTF, INF_, 0, stream>>>((const float*)d_in[2], flag, TT);
    gat_tt<bf16, 0><<<OUTF, INF_, 0, stream>>>((const bf16*)d_in[2], flag, TT);

    gat_proj_t<float, 1><<<NN / 16, 256, 0, stream>>>(
        (const float*)d_in[0], TT, (const float*)d_in[3], flag, HTt, e1c, e2c);
    gat_proj_t<bf16, 0><<<NN / 16, 256, 0, stream>>>(
        (const bf16*)d_in[0], TT, (const bf16*)d_in[3], flag, HTt, e1c, e2c);

    gat_attn<<<(NN / 64) * JSPLIT, 256, 0, stream>>>(adj, HTt, e1c, e2c, numP, denP);

    gat_fin<<<NN * OUTF / 4 / 256, 256, 0, stream>>>(numP, denP, flag, d_out);
}

// Round 10
// 439.602 us; speedup vs baseline: 1.3217x; 1.3217x over previous
//
#include <hip/hip_runtime.h>
#include <hip/hip_bf16.h>
#include <cstdint>
#include <cstddef>

#define NN     8192
#define INF_   256
#define OUTF   128
#define ALPHA  0.2f
#define LOG2E  1.4426950408889634f
#define JSPLIT 8
#define CHUNK  (NN / JSPLIT)   // 1024 j per block

typedef __bf16 bf16;
typedef unsigned int u32;
typedef unsigned long long u64;
typedef __attribute__((ext_vector_type(8))) __bf16 bf16x8;
typedef __attribute__((ext_vector_type(4))) float f32x4;
typedef __attribute__((ext_vector_type(4))) unsigned int u32x4;
typedef __attribute__((ext_vector_type(8))) unsigned short u16x8;
typedef __attribute__((ext_vector_type(4))) unsigned short u16x4;

// ---------------------------------------------------------------------------
// Dtype detector: read x's first 2048 uint16s as bf16. fp32 storage -> words
// are fp32 mantissa fragments -> huge exponents; bf16 storage -> N(0,1).
// flag = 1 -> tensors are fp32 (confirmed R2-R9); 0 -> bf16.
// ---------------------------------------------------------------------------
__global__ void gat_detect(const unsigned short* __restrict__ xr, int* __restrict__ flag)
{
    const int lane = threadIdx.x & 63;
    float m = 0.f;
    #pragma unroll
    for (int t = 0; t < 32; ++t) {
        const unsigned short u = xr[lane * 32 + t];
        const float v = fabsf((float)__builtin_bit_cast(bf16, u));
        if (v == v) m = fmaxf(m, v);
    }
    #pragma unroll
    for (int d = 1; d < 64; d <<= 1) m = fmaxf(m, __shfl_xor(m, d));
    if (lane == 0) *flag = (m > 100.f) ? 1 : 0;
}

// dtype-generic helpers ------------------------------------------------------
static __device__ __forceinline__ bf16  loadS(const bf16* p)  { return *p; }
static __device__ __forceinline__ bf16  loadS(const float* p) { return (bf16)*p; }
static __device__ __forceinline__ float loadF(const bf16* p)  { return (float)*p; }
static __device__ __forceinline__ float loadF(const float* p) { return *p; }
static __device__ __forceinline__ void load4(const float* p, bf16* d) {
    const f32x4 v = *(const f32x4*)p;
    #pragma unroll
    for (int t = 0; t < 4; ++t) d[t] = (bf16)v[t];
}
static __device__ __forceinline__ void load4(const bf16* p, bf16* d) {
    *(u16x4*)d = *(const u16x4*)p;
}

// ---------------------------------------------------------------------------
// trans transpose: TT[n][k] = bf16(trans[k][n]).
// ---------------------------------------------------------------------------
template <typename T, int WANT>
__global__ void gat_tt(const T* __restrict__ trans, const int* __restrict__ flag,
                       bf16* __restrict__ TT)
{
    if (*flag != WANT) return;
    const int n = blockIdx.x;      // 0..127
    const int k = threadIdx.x;     // 0..255
    TT[n * INF_ + k] = loadS(trans + k * OUTF + n);
}

// ---------------------------------------------------------------------------
// Projection: h = x @ trans, 16 rows/block (grid 512 -> 2 blocks/CU).
// x staged in LDS (17 KB total); TT b-frags read straight from L1/L2 (64 KB
// hot). Outputs tiled HTt[i>>5][n][i&31], e1c/e2c (pre-scaled by log2e).
// ---------------------------------------------------------------------------
template <typename T, int WANT>
__global__ __launch_bounds__(256, 2)
void gat_proj_t(const T* __restrict__ x, const bf16* __restrict__ TT,
                const T* __restrict__ aw, const int* __restrict__ flag,
                bf16* __restrict__ HTt, float* __restrict__ e1c, float* __restrict__ e2c)
{
    if (*flag != WANT) return;

    __shared__ bf16  xs[16][264];
    __shared__ float hl[16][129];

    const int tid  = threadIdx.x;
    const int wave = tid >> 6;
    const int lane = tid & 63;
    const int m    = lane & 15;
    const int q    = lane >> 4;
    const int i0   = blockIdx.x * 16;
    const int n0   = wave * 32;

    // stage x: 16 rows x 256 cols (4096 elems), coalesced, cvt to bf16
    #pragma unroll
    for (int it = 0; it < 4; ++it) {
        const int e = it * 1024 + tid * 4;
        bf16 tmp[4];
        load4(x + (size_t)i0 * INF_ + e, tmp);
        *(u16x4*)&xs[e >> 8][e & 255] = *(u16x4*)tmp;
    }
    __syncthreads();

    f32x4 acc0 = {}, acc1 = {};
    #pragma unroll
    for (int ks = 0; ks < INF_; ks += 32) {
        const bf16x8 a  = *(const bf16x8*)&xs[m][ks + q * 8];          // A[m][k]
        const bf16x8 b0 = *(const bf16x8*)(TT + (n0 + m) * INF_ + ks + q * 8);
        const bf16x8 b1 = *(const bf16x8*)(TT + (n0 + 16 + m) * INF_ + ks + q * 8);
        acc0 = __builtin_amdgcn_mfma_f32_16x16x32_bf16(a, b0, acc0, 0, 0, 0);
        acc1 = __builtin_amdgcn_mfma_f32_16x16x32_bf16(a, b1, acc1, 0, 0, 0);
    }

    // C/D layout: col = lane&15, row = q*4 + reg
    #pragma unroll
    for (int r = 0; r < 4; ++r) {
        hl[q * 4 + r][n0 + m]      = acc0[r];
        hl[q * 4 + r][n0 + 16 + m] = acc1[r];
    }
    __syncthreads();

    {   // e1/e2: 16 threads per row, 8 cols each, reduce over 16 lanes
        const int r = tid >> 4, tn = tid & 15;
        float s1 = 0.f, s2 = 0.f;
        #pragma unroll
        for (int u = 0; u < 8; ++u) {
            const float hv = hl[r][tn * 8 + u];
            s1 += hv * loadF(aw + tn * 8 + u);
            s2 += hv * loadF(aw + OUTF + tn * 8 + u);
        }
        #pragma unroll
        for (int d = 1; d < 16; d <<= 1) {
            s1 += __shfl_xor(s1, d);
            s2 += __shfl_xor(s2, d);
        }
        if (tn == 0) {
            e1c[i0 + r] = s1 * LOG2E;
            e2c[i0 + r] = s2 * LOG2E;
        }
    }

    {   // HTt tiled write: HTt[i>>5][n][i&31]; this block covers half a 32-tile
        const int n = tid >> 1, ih = tid & 1;
        u16x8 pk;
        #pragma unroll
        for (int v = 0; v < 8; ++v)
            pk[v] = __builtin_bit_cast(unsigned short, (bf16)hl[ih * 8 + v][n]);
        bf16* base = HTt + (size_t)(i0 >> 5) * 4096 + n * 32
                   + ((i0 >> 4) & 1) * 16 + ih * 8;
        *(u16x8*)base = pk;
    }
}

// ---------------------------------------------------------------------------
// FUSED adj-stream + masked-softmax-attention partials (R8 form — best
// measured; R5/R6/R9 manual-scheduling variants all regressed 2x).
// Grid 1024 = 4 blocks/CU, no LDS, no barriers, plain loads at loop top;
// 16 waves/CU TLP hides the per-window adj latency. Per 64-j window:
//   16 coalesced dword loads (row r, j = w*64 + lane)  -> 4 KB HBM stream
//   16 __ballot -> u64 row-masks; lane r keeps row r's mask
//   __shfl(mask, m) -> lane (m,q) gets row m's bits for its A-fragment
//   2 x 32-j MFMA steps vs L2-hot tiled HTt (8 MFMAs each, all 128 features)
// jc = bid & 7 pins each XCD to one HTt/e2c j-slice (L2-resident).
// ---------------------------------------------------------------------------
__global__ __launch_bounds__(256, 4)
void gat_attn(const int* __restrict__ adj, const bf16* __restrict__ HTt,
              const float* __restrict__ e1c, const float* __restrict__ e2c,
              float* __restrict__ numP, float* __restrict__ denP)
{
    const int tid  = threadIdx.x;
    const int wave = tid >> 6;
    const int lane = tid & 63;
    const int m    = lane & 15;
    const int q    = lane >> 4;
    const int jc   = blockIdx.x & (JSPLIT - 1);
    const int ig   = blockIdx.x / JSPLIT;
    const int rbase = ig * 64 + wave * 16;
    const int j0    = jc * CHUNK;

    const float e1 = e1c[rbase + m];
    const int*   ap = adj + (size_t)rbase * NN + j0 + lane;
    const float* pe = e2c + j0 + q * 8;
    const bf16*  pb = HTt + (size_t)(j0 >> 5) * 4096 + m * 32 + q * 8;

    f32x4 acc[8] = {};
    float rs = 0.f;

    for (int w = 0; w < CHUNK / 64; ++w) {          // 16 windows of 64 j
        // stream this wave's 16 rows x 64 j of adj (bit j = lane for ballot)
        int v[16];
        #pragma unroll
        for (int r = 0; r < 16; ++r)
            v[r] = ap[(size_t)r * NN + w * 64];

        // pack: row r -> 64-bit mask; park row r's mask in lane r
        u32 mlo = 0, mhi = 0;
        #pragma unroll
        for (int r = 0; r < 16; ++r) {
            const u64 b = __ballot(v[r] != 0);
            if (lane == r) { mlo = (u32)b; mhi = (u32)(b >> 32); }
        }
        // lane (m,q) pulls row m's mask halves
        const u32 wlo = __shfl(mlo, m);
        const u32 whi = __shfl(mhi, m);

        #pragma unroll
        for (int h = 0; h < 2; ++h) {               // two 32-j MFMA steps
            const u32 wb = h ? whi : wlo;
            const int j  = w * 64 + h * 32;
            const f32x4 e2a = *(const f32x4*)(pe + j);
            const f32x4 e2b = *(const f32x4*)(pe + j + 4);

            bf16x8 af;   // A-fragment: A[m][k=q*8+t], leaky-relu in log2 domain
            #pragma unroll
            for (int t = 0; t < 4; ++t) {
                float sv = e1 + e2a[t];
                sv = fmaxf(sv, ALPHA * sv);
                const float p = ((wb >> (q * 8 + t)) & 1u) ? __builtin_amdgcn_exp2f(sv) : 0.f;
                rs += p;
                af[t] = (bf16)p;
            }
            #pragma unroll
            for (int t = 0; t < 4; ++t) {
                float sv = e1 + e2b[t];
                sv = fmaxf(sv, ALPHA * sv);
                const float p = ((wb >> (q * 8 + 4 + t)) & 1u) ? __builtin_amdgcn_exp2f(sv) : 0.f;
                rs += p;
                af[4 + t] = (bf16)p;
            }

            const bf16* pbs = pb + (size_t)(j >> 5) * 4096;
            #pragma unroll
            for (int t = 0; t < 8; ++t) {
                const bf16x8 b = __builtin_bit_cast(bf16x8, *(const u32x4*)(pbs + t * 512));
                acc[t] = __builtin_amdgcn_mfma_f32_16x16x32_bf16(af, b, acc[t], 0, 0, 0);
            }
        }
    }

    // row-sum: lanes {m, m+16, m+32, m+48} hold the 4 q-slices of row m
    rs += __shfl_xor(rs, 16);
    rs += __shfl_xor(rs, 32);
    if (lane < 16) denP[(size_t)jc * NN + rbase + m] = rs;

    // C/D layout: col = lane&15, row = q*4 + r -> unique partial slot
    #pragma unroll
    for (int t = 0; t < 8; ++t)
        #pragma unroll
        for (int r = 0; r < 4; ++r)
            numP[((size_t)jc * NN + rbase + q * 4 + r) * OUTF + t * 16 + m] = acc[t][r];
}

// ---------------------------------------------------------------------------
// Finalize: out = elu( (sum_s numP) / (sum_s denP) )
// ---------------------------------------------------------------------------
__global__ __launch_bounds__(256)
void gat_fin(const float* __restrict__ numP, const float* __restrict__ denP,
             const int* __restrict__ flag, void* __restrict__ outv)
{
    const int g  = blockIdx.x * 256 + threadIdx.x;   // one thread per 4 elems
    const int i  = g >> 5;
    const int c4 = g & 31;
    float d = 0.f;
    f32x4 v = {0.f, 0.f, 0.f, 0.f};
    #pragma unroll
    for (int s = 0; s < JSPLIT; ++s) {
        d += denP[(size_t)s * NN + i];
        const f32x4 u = *(const f32x4*)(numP + ((size_t)s * NN + i) * OUTF + c4 * 4);
        #pragma unroll
        for (int t = 0; t < 4; ++t) v[t] += u[t];
    }
    #pragma unroll
    for (int t = 0; t < 4; ++t) {
        const float u = v[t] / d;
        v[t] = (u > 0.f) ? u : __builtin_amdgcn_exp2f(u * LOG2E) - 1.f;  // elu
    }
    const size_t off = (size_t)i * OUTF + c4 * 4;
    if (*flag) {
        *(f32x4*)((float*)outv + off) = v;
    } else {
        u16x4 pk;
        #pragma unroll
        for (int t = 0; t < 4; ++t)
            pk[t] = __builtin_bit_cast(unsigned short, (bf16)v[t]);
        *(u16x4*)((__hip_bfloat16*)outv + off) = pk;
    }
}

// ---------------------------------------------------------------------------
extern "C" void kernel_launch(void* const* d_in, const int* in_sizes, int n_in,
                              void* d_out, int out_size, void* d_ws, size_t ws_size,
                              hipStream_t stream)
{
    const int* adj = (const int*)d_in[1];

    // ws layout (bytes):
    // HTt 2MB | e1c 32KB | e2c 32KB | flag 256B | TT 64KB | numP 32MB | denP 256KB
    char* w = (char*)d_ws;
    bf16*  HTt   = (bf16*)w;   w += (size_t)OUTF * NN * 2;
    float* e1c   = (float*)w;  w += NN * 4;
    float* e2c   = (float*)w;  w += NN * 4;
    int*   flag  = (int*)w;    w += 256;
    bf16*  TT    = (bf16*)w;   w += (size_t)OUTF * INF_ * 2;
    float* numP  = (float*)w;  w += (size_t)JSPLIT * NN * OUTF * 4;
    float* denP  = (float*)w;

    gat_detect<<<1, 64, 0, stream>>>((const unsigned short*)d_in[0], flag);

    gat_tt<float, 1><<<OUTF, INF_, 0, stream>>>((const float*)d_in[2], flag, TT);
    gat_tt<bf16, 0><<<OUTF, INF_, 0, stream>>>((const bf16*)d_in[2], flag, TT);

    gat_proj_t<float, 1><<<NN / 16, 256, 0, stream>>>(
        (const float*)d_in[0], TT, (const float*)d_in[3], flag, HTt, e1c, e2c);
    gat_proj_t<bf16, 0><<<NN / 16, 256, 0, stream>>>(
        (const bf16*)d_in[0], TT, (const bf16*)d_in[3], flag, HTt, e1c, e2c);

    gat_attn<<<(NN / 64) * JSPLIT, 256, 0, stream>>>(adj, HTt, e1c, e2c, numP, denP);

    gat_fin<<<NN * OUTF / 4 / 256, 256, 0, stream>>>(numP, denP, flag, d_out);
}